// Round 14
// baseline (284.296 us; speedup 1.0000x reference)
//
#include <hip/hip_runtime.h>
#include <hip/hip_bf16.h>
#include <math.h>

#define NROWS 8192
#define DIM   768
#define NKB   (DIM / 64)         // 12 k-chunks of 64
#define FCH   8192               // fp8 chunk: 128 rows x 64 cols = 8 KB
#define FPAN  (NKB * FCH)        // fp8 panel: 128 rows x 768 = 98304 B
#define NT128 (NROWS / 128)      // 64 row-blocks (chunk granularity)
#define NTILES (NT128 * (NT128 + 1) / 2)   // 2080 (fallback grid)
#define NTIL3 1056               // 256x128 tiles, q >= 2p
#define PACK8B ((size_t)NT128 * FPAN)      // 6.29 MB
#define LDSB  49152              // 2 x 24 KB
#define UNITY 0x7F7F7F7F         // E8M0 exponent 127 = 2^0 in every byte

typedef __attribute__((ext_vector_type(4)))  float  f32x4;
typedef __attribute__((ext_vector_type(16))) float  f32x16;
typedef __attribute__((ext_vector_type(8)))  __bf16 bf16x8;
typedef __attribute__((ext_vector_type(4)))  __bf16 bf16x4;
typedef __attribute__((ext_vector_type(4)))  int    i32x4;
typedef __attribute__((ext_vector_type(8)))  int    i32x8;

__device__ __forceinline__ void gload_lds16(const void* g, void* l) {
  __builtin_amdgcn_global_load_lds(
      (const __attribute__((address_space(1))) void*)g,
      (__attribute__((address_space(3))) void*)l, 16, 0, 0);
}

// ---------------------------------------------------------------------------
// Kernel A: fused fp8-pack + prep. One wave per row. f32 -> exact f32 sq-norm
// AND fp8 e4m3 (HW v_cvt_pk_fp8_f32) into ROW-MAJOR 64B-row chunk layout with
// the R7-class 16B-granule XOR swizzle PRE-APPLIED:
//   chunk(rb, kb) = 128 rows x 64 k; element (r,c) at (r*64 + c) ^ (((r>>1)&3)<<4)
// 4B stores: XOR touches bits 4-5 only -> stays in one 16B granule; the XOR is
// constant per row (per wave) -> global stores remain coalesced.
// ---------------------------------------------------------------------------
__global__ __launch_bounds__(256) void koleo_pack8(const float* __restrict__ X,
                                                   float* __restrict__ sq,
                                                   unsigned int* __restrict__ minbits,
                                                   char* __restrict__ xbf) {
  const int row  = blockIdx.x * 4 + (threadIdx.x >> 6);
  const int lane = threadIdx.x & 63;
  const int rb = row >> 7, rr = row & 127;
  const int swz = ((rr >> 1) & 3) << 4;
  const float* xr = X + (size_t)row * DIM;
  float s = 0.f;
#pragma unroll
  for (int i = 0; i < 3; ++i) {            // 768 = 3 * 64 lanes * 4 floats
    const int c0 = lane * 4 + i * 256;
    f32x4 v = *(const f32x4*)(xr + c0);
    s += v.x * v.x + v.y * v.y + v.z * v.z + v.w * v.w;
    int pk = __builtin_amdgcn_cvt_pk_fp8_f32(v.x, v.y, 0, false);
    pk     = __builtin_amdgcn_cvt_pk_fp8_f32(v.z, v.w, pk, true);
    const int kb = c0 >> 6;
    const int c  = c0 & 63;
    const int off = (rr * 64 + c) ^ swz;
    *(int*)(xbf + (size_t)rb * FPAN + (size_t)kb * FCH + off) = pk;
  }
#pragma unroll
  for (int m = 32; m >= 1; m >>= 1) s += __shfl_xor(s, m, 64);
  if (lane == 0) {
    sq[row]      = s;
    minbits[row] = 0x7F800000u;            // +inf
  }
}

// ---------------------------------------------------------------------------
// Kernel B: 256x128 tiles (q >= 2p; dups harmless under min), 8 waves
// (4 row x 2 col slices of 64x64), 2-phase dbuf (R13 frame, validated).
// R14 core swap: v_mfma_scale_f32_32x32x64_f8f6f4 with UNITY scales
// (intrinsic math validated R9 absmax=0.0) — 4 MFMA/epoch/wave (was 32),
// 2x MFMA rate (4686 TF m59). Fragments: lane l = kh*32+row32 holds row
// (l&31), k-half (l>>5): two b128 at a0 and a0^16 (A/B symmetric -> k-perm
// cancels). Registers: acc 4x f32x16 = 64 + 4 octets = 32 + addr ~ 120.
// LDS 48 KB -> 2 blocks/CU. Segment ordering validated R6/R13.
// ---------------------------------------------------------------------------
#define LOADO(dst, base, R0)                                                  \
  { const int rr_ = (R0) + lrow;                                              \
    const int a0_ = ((rr_ * 64 + kh32) ^ (((rr_ >> 1) & 3) << 4));            \
    i32x4 lo_ = *(const i32x4*)((base) + a0_);                                \
    i32x4 hi_ = *(const i32x4*)((base) + (a0_ ^ 16));                         \
    dst = __builtin_shufflevector(lo_, hi_, 0, 1, 2, 3, 4, 5, 6, 7); }

__global__ __launch_bounds__(512, 4) void koleo_t32(const char* __restrict__ xbf,
                                                    const float* __restrict__ sq,
                                                    unsigned int* __restrict__ minbits) {
  extern __shared__ char lds[];            // 49152 bytes

  // segment-ordered tile map: ti in [0,32) (256-row A), tj in [0,64) (128-col B)
  const int b = blockIdx.x;
  int ti, tj;
  if (b < 272) {                           // T0: ti in [0,16)
    int rem = b, rl = 32; ti = 0;
    while (rem >= rl) { rem -= rl; ++ti; rl -= 2; }
    tj = 2 * ti + rem;
  } else if (b < 784) {                    // bands: ti [0,16) x tj [32+8g,40+8g)
    const int idx = b - 272;
    const int g = idx >> 7, rr = idx & 127;
    ti = rr >> 3; tj = 32 + g * 8 + (rr & 7);
  } else {                                 // T1: ti in [16,32)
    int rem = b - 784, rl = 32; ti = 16;
    while (rem >= rl) { rem -= rl; ++ti; rl -= 2; }
    tj = 2 * ti + rem;
  }
  const int i0 = ti * 256, j0 = tj * 128;

  const int tid  = threadIdx.x;
  const int lane = tid & 63;
  const int wave = tid >> 6;               // 0..7
  const int wr   = wave >> 1;              // 0..3 row 64-slice of 256
  const int wc   = wave & 1;               // 0..1 col 64-slice of 128
  const int lrow = lane & 31;              // fragment row within 32-block
  const int kh32 = (lane >> 5) * 32;       // k-half byte offset

  // staging role (R13): 24 x 1KB segments/chunk; wave stages s = wave*3+k
  const char* ssrc[3];
  int sdst[3];
#pragma unroll
  for (int k = 0; k < 3; ++k) {
    const int s  = wave * 3 + k;
    const int rb = (s < 16) ? (2 * ti + (s >> 3)) : tj;
    const int of = (s < 16) ? ((s & 7) * 1024) : ((s - 16) * 1024);
    ssrc[k] = xbf + (size_t)rb * FPAN + of + lane * 16;
    sdst[k] = s * 1024;
  }

  f32x16 acc00 = {}, acc01 = {}, acc10 = {}, acc11 = {};

  // ---- prologue: stage K-chunk 0 into buffer 0 ---------------------------
#pragma unroll
  for (int k = 0; k < 3; ++k)
    gload_lds16(ssrc[k], lds + sdst[k]);
  asm volatile("s_waitcnt vmcnt(0)" ::: "memory");
  __builtin_amdgcn_s_barrier();

  // ---- main K-loop: one barrier per chunk epoch ---------------------------
  for (int t = 0; t < NKB; ++t) {
    char* buf  = lds + (t & 1) * 24576;
    char* nbuf = lds + ((t + 1) & 1) * 24576;
    const bool more = (t + 1 < NKB);

    if (more) {
#pragma unroll
      for (int k = 0; k < 3; ++k)
        gload_lds16(ssrc[k] + (size_t)(t + 1) * FCH, nbuf + sdst[k]);
    }

    // fragments: A from chunk (wr>>1), rows (wr&1)*64 + mi*32; B chunk at 16K
    i32x8 a0, a1, b0, b1;
    const char* abase = buf + (wr >> 1) * 8192;
    LOADO(a0, abase, (wr & 1) * 64);
    LOADO(a1, abase, (wr & 1) * 64 + 32);
    LOADO(b0, buf + 16384, wc * 64);
    LOADO(b1, buf + 16384, wc * 64 + 32);

    __builtin_amdgcn_s_setprio(1);
    acc00 = __builtin_amdgcn_mfma_scale_f32_32x32x64_f8f6f4(
        a0, b0, acc00, 0, 0, 0, UNITY, 0, UNITY);
    acc01 = __builtin_amdgcn_mfma_scale_f32_32x32x64_f8f6f4(
        a0, b1, acc01, 0, 0, 0, UNITY, 0, UNITY);
    acc10 = __builtin_amdgcn_mfma_scale_f32_32x32x64_f8f6f4(
        a1, b0, acc10, 0, 0, 0, UNITY, 0, UNITY);
    acc11 = __builtin_amdgcn_mfma_scale_f32_32x32x64_f8f6f4(
        a1, b1, acc11, 0, 0, 0, UNITY, 0, UNITY);
    __builtin_amdgcn_s_setprio(0);

    if (more) asm volatile("s_waitcnt vmcnt(0)" ::: "memory");
    __builtin_amdgcn_s_barrier();
  }

  // ---- epilogue: d2, diag mask, row+col min, atomicMin ---------------------
  // 32x32 C/D layout (m74/m101; shape-determined m127/m128):
  //   col = lane&31, row = (reg&3) + 8*(reg>>2) + 4*(lane>>5)
  const int kh = lane >> 5;
  const float sqj0 = sq[j0 + wc * 64 + lrow];
  const float sqj1 = sq[j0 + wc * 64 + 32 + lrow];
  const int gj0 = j0 + wc * 64 + lrow;
  const int gj1 = gj0 + 32;
  float colmin0 = INFINITY, colmin1 = INFINITY;
#pragma unroll
  for (int mi = 0; mi < 2; ++mi) {
    const f32x16 an0 = mi ? acc10 : acc00;
    const f32x16 an1 = mi ? acc11 : acc01;
    const int gib = i0 + wr * 64 + mi * 32 + 4 * kh;
#pragma unroll
    for (int reg = 0; reg < 16; ++reg) {
      const int gi = gib + (reg & 3) + 8 * (reg >> 2);
      const float si = sq[gi];
      float d20 = fmaxf(si + sqj0 - 2.0f * an0[reg], 0.0f);
      float d21 = fmaxf(si + sqj1 - 2.0f * an1[reg], 0.0f);
      if (gi == gj0) d20 = INFINITY;
      if (gi == gj1) d21 = INFINITY;
      colmin0 = fminf(colmin0, d20);
      colmin1 = fminf(colmin1, d21);
      float rowmin = fminf(d20, d21);
      rowmin = fminf(rowmin, __shfl_xor(rowmin, 1, 64));
      rowmin = fminf(rowmin, __shfl_xor(rowmin, 2, 64));
      rowmin = fminf(rowmin, __shfl_xor(rowmin, 4, 64));
      rowmin = fminf(rowmin, __shfl_xor(rowmin, 8, 64));
      rowmin = fminf(rowmin, __shfl_xor(rowmin, 16, 64));
      if (lrow == 0)
        atomicMin(minbits + gi, __float_as_uint(rowmin));
    }
  }
  colmin0 = fminf(colmin0, __shfl_xor(colmin0, 32, 64));
  colmin1 = fminf(colmin1, __shfl_xor(colmin1, 32, 64));
  if (kh == 0) {
    atomicMin(minbits + gj0, __float_as_uint(colmin0));
    atomicMin(minbits + gj1, __float_as_uint(colmin1));
  }
}

// ---------------------------------------------------------------------------
// Fallback (ws too small): bf16 f32-load + in-loop cvt staging, 128^2 tiles.
// ---------------------------------------------------------------------------
__global__ __launch_bounds__(256) void koleo_prep_fb(const float* __restrict__ X,
                                                     float* __restrict__ sq,
                                                     unsigned int* __restrict__ minbits) {
  const int row  = blockIdx.x * 4 + (threadIdx.x >> 6);
  const int lane = threadIdx.x & 63;
  const float* xr = X + (size_t)row * DIM;
  float s = 0.f;
#pragma unroll
  for (int i = 0; i < 3; ++i) {
    f32x4 v = *(const f32x4*)(xr + lane * 4 + i * 256);
    s += v.x * v.x + v.y * v.y + v.z * v.z + v.w * v.w;
  }
#pragma unroll
  for (int m = 32; m >= 1; m >>= 1) s += __shfl_xor(s, m, 64);
  if (lane == 0) { sq[row] = s; minbits[row] = 0x7F800000u; }
}

__global__ __launch_bounds__(256) void koleo_tile_fb(const float* __restrict__ X,
                                                     const float* __restrict__ sq,
                                                     unsigned int* __restrict__ minbits) {
  __shared__ __align__(16) char sA[16384];
  __shared__ __align__(16) char sB[16384];
  int rem = blockIdx.x, ti = 0, rowlen = NT128;
  while (rem >= rowlen) { rem -= rowlen; ++ti; --rowlen; }
  const int tj = ti + rem;
  const int i0 = ti * 128, j0 = tj * 128;
  const int tid = threadIdx.x, lane = tid & 63, wave = tid >> 6;
  const int wr = wave >> 1, wc = wave & 1;
  f32x4 acc[4][4] = {};
  for (int k0 = 0; k0 < DIM; k0 += 64) {
    __syncthreads();
#pragma unroll
    for (int it = 0; it < 8; ++it) {
      const int idx = tid + it * 256;
      const int r = idx >> 4, c4 = idx & 15;
      f32x4 va = *(const f32x4*)(X + (size_t)(i0 + r) * DIM + k0 + c4 * 4);
      f32x4 vb = *(const f32x4*)(X + (size_t)(j0 + r) * DIM + k0 + c4 * 4);
      bf16x4 ha, hb;
      ha[0] = (__bf16)va.x; ha[1] = (__bf16)va.y; ha[2] = (__bf16)va.z; ha[3] = (__bf16)va.w;
      hb[0] = (__bf16)vb.x; hb[1] = (__bf16)vb.y; hb[2] = (__bf16)vb.z; hb[3] = (__bf16)vb.w;
      int off = (r * 128 + c4 * 8) ^ ((r & 7) << 4);
      *(bf16x4*)(sA + off) = ha;
      *(bf16x4*)(sB + off) = hb;
    }
    __syncthreads();
#pragma unroll
    for (int ks = 0; ks < 2; ++ks) {
      bf16x8 af[4], bfr[4];
#pragma unroll
      for (int m = 0; m < 4; ++m) {
        const int ra = wr * 64 + m * 16 + (lane & 15);
        af[m]  = *(const bf16x8*)(sA + ((ra * 128 + ks * 64 + (lane >> 4) * 16) ^ ((ra & 7) << 4)));
        const int rb2 = wc * 64 + m * 16 + (lane & 15);
        bfr[m] = *(const bf16x8*)(sB + ((rb2 * 128 + ks * 64 + (lane >> 4) * 16) ^ ((rb2 & 7) << 4)));
      }
#pragma unroll
      for (int m = 0; m < 4; ++m)
#pragma unroll
        for (int n = 0; n < 4; ++n)
          acc[m][n] = __builtin_amdgcn_mfma_f32_16x16x32_bf16(af[m], bfr[n], acc[m][n], 0, 0, 0);
    }
  }
  const int cg = lane >> 4, cl = lane & 15;
  float sqj[4], colmin[4];
#pragma unroll
  for (int n = 0; n < 4; ++n) { sqj[n] = sq[j0 + wc * 64 + n * 16 + cl]; colmin[n] = INFINITY; }
#pragma unroll
  for (int m = 0; m < 4; ++m) {
#pragma unroll
    for (int r = 0; r < 4; ++r) {
      const int gi = i0 + wr * 64 + m * 16 + cg * 4 + r;
      const float si = sq[gi];
      float rowmin = INFINITY;
#pragma unroll
      for (int n = 0; n < 4; ++n) {
        const int gj = j0 + wc * 64 + n * 16 + cl;
        float d2 = si + sqj[n] - 2.0f * acc[m][n][r];
        d2 = fmaxf(d2, 0.0f);
        if (gi == gj) d2 = INFINITY;
        rowmin = fminf(rowmin, d2);
        colmin[n] = fminf(colmin[n], d2);
      }
      rowmin = fminf(rowmin, __shfl_xor(rowmin, 1, 64));
      rowmin = fminf(rowmin, __shfl_xor(rowmin, 2, 64));
      rowmin = fminf(rowmin, __shfl_xor(rowmin, 4, 64));
      rowmin = fminf(rowmin, __shfl_xor(rowmin, 8, 64));
      if (cl == 0) atomicMin(minbits + gi, __float_as_uint(rowmin));
    }
  }
  if (ti != tj) {
#pragma unroll
    for (int n = 0; n < 4; ++n) {
      float cm = colmin[n];
      cm = fminf(cm, __shfl_xor(cm, 16, 64));
      cm = fminf(cm, __shfl_xor(cm, 32, 64));
      if (cg == 0) atomicMin(minbits + j0 + wc * 64 + n * 16 + cl, __float_as_uint(cm));
    }
  }
}

// ---------------------------------------------------------------------------
// Final: loss = -mean(log(sqrt(min_d2) + eps)), single block
// ---------------------------------------------------------------------------
__global__ __launch_bounds__(1024) void koleo_final(const unsigned int* __restrict__ minbits,
                                                    float* __restrict__ out) {
  __shared__ float wsum[16];
  float s = 0.f;
  for (int i = threadIdx.x; i < NROWS; i += 1024) {
    float d2 = __uint_as_float(minbits[i]);
    s += logf(sqrtf(d2) + 1e-8f);
  }
#pragma unroll
  for (int m = 32; m >= 1; m >>= 1) s += __shfl_xor(s, m, 64);
  const int wv = threadIdx.x >> 6, ln = threadIdx.x & 63;
  if (ln == 0) wsum[wv] = s;
  __syncthreads();
  if (wv == 0) {
    float t = (ln < 16) ? wsum[ln] : 0.f;
#pragma unroll
    for (int m = 8; m >= 1; m >>= 1) t += __shfl_xor(t, m, 64);
    if (ln == 0) out[0] = -t / (float)NROWS;
  }
}

// ---------------------------------------------------------------------------
extern "C" void kernel_launch(void* const* d_in, const int* in_sizes, int n_in,
                              void* d_out, int out_size, void* d_ws, size_t ws_size,
                              hipStream_t stream) {
  const float* X = (const float*)d_in[0];
  float* out = (float*)d_out;
  unsigned int* minbits = (unsigned int*)d_ws;                       // 32 KB
  float* sq = (float*)((char*)d_ws + NROWS * sizeof(unsigned int));  // 32 KB
  char* xbf = (char*)d_ws + 65536;                                   // 6.29 MB

  const size_t need = 65536 + PACK8B;
  if (ws_size >= need) {
    koleo_pack8<<<NROWS / 4, 256, 0, stream>>>(X, sq, minbits, xbf);
    koleo_t32<<<NTIL3, 512, LDSB, stream>>>(xbf, sq, minbits);
  } else {
    koleo_prep_fb<<<NROWS / 4, 256, 0, stream>>>(X, sq, minbits);
    koleo_tile_fb<<<NTILES, 256, 0, stream>>>(X, sq, minbits);
  }
  koleo_final<<<1, 1024, 0, stream>>>(minbits, out);
}

// Round 15
// 255.828 us; speedup vs baseline: 1.1113x; 1.1113x over previous
//
#include <hip/hip_runtime.h>
#include <hip/hip_bf16.h>
#include <math.h>

#define NROWS 8192
#define DIM   768
#define NKB   (DIM / 64)         // 12 k-chunks of 64
#define FCH   8192               // fp8 chunk: 128 rows x 64 cols = 8 KB
#define FPAN  (NKB * FCH)        // fp8 panel: 128 rows x 768 = 98304 B
#define NT128 (NROWS / 128)      // 64 row-blocks (chunk granularity)
#define NTILES (NT128 * (NT128 + 1) / 2)   // 2080 (fallback grid)
#define NTIL3 1056               // 256x128 tiles, q >= 2p
#define PACK8B ((size_t)NT128 * FPAN)      // 6.29 MB
#define LDSB  49152              // 2 x 24 KB
#define UNITY 0x7F7F7F7F         // E8M0 exponent 127 = 2^0 in every byte

typedef __attribute__((ext_vector_type(4)))  float  f32x4;
typedef __attribute__((ext_vector_type(16))) float  f32x16;
typedef __attribute__((ext_vector_type(8)))  __bf16 bf16x8;
typedef __attribute__((ext_vector_type(4)))  __bf16 bf16x4;
typedef __attribute__((ext_vector_type(4)))  int    i32x4;
typedef __attribute__((ext_vector_type(8)))  int    i32x8;

__device__ __forceinline__ void gload_lds16(const void* g, void* l) {
  __builtin_amdgcn_global_load_lds(
      (const __attribute__((address_space(1))) void*)g,
      (__attribute__((address_space(3))) void*)l, 16, 0, 0);
}

// ---------------------------------------------------------------------------
// Kernel A: fused fp8-pack + prep. One wave per row. f32 -> exact f32 sq-norm
// AND fp8 e4m3 (HW v_cvt_pk_fp8_f32) into ROW-MAJOR 64B-row chunk layout with
// the R7-class 16B-granule XOR swizzle PRE-APPLIED:
//   chunk(rb, kb) = 128 rows x 64 k; element (r,c) at (r*64 + c) ^ (((r>>1)&3)<<4)
// 4B stores: XOR touches bits 4-5 only -> stays in one 16B granule; the XOR is
// constant per row (per wave) -> global stores remain coalesced.
// ---------------------------------------------------------------------------
__global__ __launch_bounds__(256) void koleo_pack8(const float* __restrict__ X,
                                                   float* __restrict__ sq,
                                                   unsigned int* __restrict__ minbits,
                                                   char* __restrict__ xbf) {
  const int row  = blockIdx.x * 4 + (threadIdx.x >> 6);
  const int lane = threadIdx.x & 63;
  const int rb = row >> 7, rr = row & 127;
  const int swz = ((rr >> 1) & 3) << 4;
  const float* xr = X + (size_t)row * DIM;
  float s = 0.f;
#pragma unroll
  for (int i = 0; i < 3; ++i) {            // 768 = 3 * 64 lanes * 4 floats
    const int c0 = lane * 4 + i * 256;
    f32x4 v = *(const f32x4*)(xr + c0);
    s += v.x * v.x + v.y * v.y + v.z * v.z + v.w * v.w;
    int pk = __builtin_amdgcn_cvt_pk_fp8_f32(v.x, v.y, 0, false);
    pk     = __builtin_amdgcn_cvt_pk_fp8_f32(v.z, v.w, pk, true);
    const int kb = c0 >> 6;
    const int c  = c0 & 63;
    const int off = (rr * 64 + c) ^ swz;
    *(int*)(xbf + (size_t)rb * FPAN + (size_t)kb * FCH + off) = pk;
  }
#pragma unroll
  for (int m = 32; m >= 1; m >>= 1) s += __shfl_xor(s, m, 64);
  if (lane == 0) {
    sq[row]      = s;
    minbits[row] = 0x7F800000u;            // +inf
  }
}

// ---------------------------------------------------------------------------
// Kernel B: 256x128 tiles (q >= 2p; dups harmless under min), 8 waves
// (4 row x 2 col slices of 64x64), 2-phase dbuf (R13 frame, validated).
// R14 core swap: v_mfma_scale_f32_32x32x64_f8f6f4 with UNITY scales
// (intrinsic math validated R9 absmax=0.0) — 4 MFMA/epoch/wave (was 32),
// 2x MFMA rate (4686 TF m59). Fragments: lane l = kh*32+row32 holds row
// (l&31), k-half (l>>5): two b128 at a0 and a0^16 (A/B symmetric -> k-perm
// cancels). Registers: acc 4x f32x16 = 64 + 4 octets = 32 + addr ~ 120.
// LDS 48 KB -> 2 blocks/CU. Segment ordering validated R6/R13.
// ---------------------------------------------------------------------------
#define LOADO(dst, base, R0)                                                  \
  { const int rr_ = (R0) + lrow;                                              \
    const int a0_ = ((rr_ * 64 + kh32) ^ (((rr_ >> 1) & 3) << 4));            \
    i32x4 lo_ = *(const i32x4*)((base) + a0_);                                \
    i32x4 hi_ = *(const i32x4*)((base) + (a0_ ^ 16));                         \
    dst = __builtin_shufflevector(lo_, hi_, 0, 1, 2, 3, 4, 5, 6, 7); }

__global__ __launch_bounds__(512, 4) void koleo_t32(const char* __restrict__ xbf,
                                                    const float* __restrict__ sq,
                                                    unsigned int* __restrict__ minbits) {
  extern __shared__ char lds[];            // 49152 bytes

  // segment-ordered tile map: ti in [0,32) (256-row A), tj in [0,64) (128-col B)
  const int b = blockIdx.x;
  int ti, tj;
  if (b < 272) {                           // T0: ti in [0,16)
    int rem = b, rl = 32; ti = 0;
    while (rem >= rl) { rem -= rl; ++ti; rl -= 2; }
    tj = 2 * ti + rem;
  } else if (b < 784) {                    // bands: ti [0,16) x tj [32+8g,40+8g)
    const int idx = b - 272;
    const int g = idx >> 7, rr = idx & 127;
    ti = rr >> 3; tj = 32 + g * 8 + (rr & 7);
  } else {                                 // T1: ti in [16,32)
    int rem = b - 784, rl = 32; ti = 16;
    while (rem >= rl) { rem -= rl; ++ti; rl -= 2; }
    tj = 2 * ti + rem;
  }
  const int i0 = ti * 256, j0 = tj * 128;

  const int tid  = threadIdx.x;
  const int lane = tid & 63;
  const int wave = tid >> 6;               // 0..7
  const int wr   = wave >> 1;              // 0..3 row 64-slice of 256
  const int wc   = wave & 1;               // 0..1 col 64-slice of 128
  const int lrow = lane & 31;              // fragment row within 32-block
  const int kh32 = (lane >> 5) * 32;       // k-half byte offset

  // staging role (R13): 24 x 1KB segments/chunk; wave stages s = wave*3+k
  const char* ssrc[3];
  int sdst[3];
#pragma unroll
  for (int k = 0; k < 3; ++k) {
    const int s  = wave * 3 + k;
    const int rb = (s < 16) ? (2 * ti + (s >> 3)) : tj;
    const int of = (s < 16) ? ((s & 7) * 1024) : ((s - 16) * 1024);
    ssrc[k] = xbf + (size_t)rb * FPAN + of + lane * 16;
    sdst[k] = s * 1024;
  }

  f32x16 acc00 = {}, acc01 = {}, acc10 = {}, acc11 = {};

  // ---- prologue: stage K-chunk 0 into buffer 0 ---------------------------
#pragma unroll
  for (int k = 0; k < 3; ++k)
    gload_lds16(ssrc[k], lds + sdst[k]);
  asm volatile("s_waitcnt vmcnt(0)" ::: "memory");
  __builtin_amdgcn_s_barrier();

  // ---- main K-loop: one barrier per chunk epoch ---------------------------
  for (int t = 0; t < NKB; ++t) {
    char* buf  = lds + (t & 1) * 24576;
    char* nbuf = lds + ((t + 1) & 1) * 24576;
    const bool more = (t + 1 < NKB);

    if (more) {
#pragma unroll
      for (int k = 0; k < 3; ++k)
        gload_lds16(ssrc[k] + (size_t)(t + 1) * FCH, nbuf + sdst[k]);
    }

    // fragments: A from chunk (wr>>1), rows (wr&1)*64 + mi*32; B chunk at 16K
    i32x8 a0, a1, b0, b1;
    const char* abase = buf + (wr >> 1) * 8192;
    LOADO(a0, abase, (wr & 1) * 64);
    LOADO(a1, abase, (wr & 1) * 64 + 32);
    LOADO(b0, buf + 16384, wc * 64);
    LOADO(b1, buf + 16384, wc * 64 + 32);

    __builtin_amdgcn_s_setprio(1);
    acc00 = __builtin_amdgcn_mfma_scale_f32_32x32x64_f8f6f4(
        a0, b0, acc00, 0, 0, 0, UNITY, 0, UNITY);
    acc01 = __builtin_amdgcn_mfma_scale_f32_32x32x64_f8f6f4(
        a0, b1, acc01, 0, 0, 0, UNITY, 0, UNITY);
    acc10 = __builtin_amdgcn_mfma_scale_f32_32x32x64_f8f6f4(
        a1, b0, acc10, 0, 0, 0, UNITY, 0, UNITY);
    acc11 = __builtin_amdgcn_mfma_scale_f32_32x32x64_f8f6f4(
        a1, b1, acc11, 0, 0, 0, UNITY, 0, UNITY);
    __builtin_amdgcn_s_setprio(0);

    if (more) asm volatile("s_waitcnt vmcnt(0)" ::: "memory");
    __builtin_amdgcn_s_barrier();
  }

  // ---- epilogue: d2, diag mask, row+col min, atomicMin ---------------------
  // 32x32 C/D layout (m74/m101; shape-determined m127/m128):
  //   col = lane&31, row = (reg&3) + 8*(reg>>2) + 4*(lane>>5)
  const int kh = lane >> 5;
  const float sqj0 = sq[j0 + wc * 64 + lrow];
  const float sqj1 = sq[j0 + wc * 64 + 32 + lrow];
  const int gj0 = j0 + wc * 64 + lrow;
  const int gj1 = gj0 + 32;
  float colmin0 = INFINITY, colmin1 = INFINITY;
#pragma unroll
  for (int mi = 0; mi < 2; ++mi) {
    const f32x16 an0 = mi ? acc10 : acc00;
    const f32x16 an1 = mi ? acc11 : acc01;
    const int gib = i0 + wr * 64 + mi * 32 + 4 * kh;
#pragma unroll
    for (int reg = 0; reg < 16; ++reg) {
      const int gi = gib + (reg & 3) + 8 * (reg >> 2);
      const float si = sq[gi];
      float d20 = fmaxf(si + sqj0 - 2.0f * an0[reg], 0.0f);
      float d21 = fmaxf(si + sqj1 - 2.0f * an1[reg], 0.0f);
      if (gi == gj0) d20 = INFINITY;
      if (gi == gj1) d21 = INFINITY;
      colmin0 = fminf(colmin0, d20);
      colmin1 = fminf(colmin1, d21);
      float rowmin = fminf(d20, d21);
      rowmin = fminf(rowmin, __shfl_xor(rowmin, 1, 64));
      rowmin = fminf(rowmin, __shfl_xor(rowmin, 2, 64));
      rowmin = fminf(rowmin, __shfl_xor(rowmin, 4, 64));
      rowmin = fminf(rowmin, __shfl_xor(rowmin, 8, 64));
      rowmin = fminf(rowmin, __shfl_xor(rowmin, 16, 64));
      if (lrow == 0)
        atomicMin(minbits + gi, __float_as_uint(rowmin));
    }
  }
  colmin0 = fminf(colmin0, __shfl_xor(colmin0, 32, 64));
  colmin1 = fminf(colmin1, __shfl_xor(colmin1, 32, 64));
  if (kh == 0) {
    atomicMin(minbits + gj0, __float_as_uint(colmin0));
    atomicMin(minbits + gj1, __float_as_uint(colmin1));
  }
}

// ---------------------------------------------------------------------------
// Fallback (ws too small): bf16 f32-load + in-loop cvt staging, 128^2 tiles.
// ---------------------------------------------------------------------------
__global__ __launch_bounds__(256) void koleo_prep_fb(const float* __restrict__ X,
                                                     float* __restrict__ sq,
                                                     unsigned int* __restrict__ minbits) {
  const int row  = blockIdx.x * 4 + (threadIdx.x >> 6);
  const int lane = threadIdx.x & 63;
  const float* xr = X + (size_t)row * DIM;
  float s = 0.f;
#pragma unroll
  for (int i = 0; i < 3; ++i) {
    f32x4 v = *(const f32x4*)(xr + lane * 4 + i * 256);
    s += v.x * v.x + v.y * v.y + v.z * v.z + v.w * v.w;
  }
#pragma unroll
  for (int m = 32; m >= 1; m >>= 1) s += __shfl_xor(s, m, 64);
  if (lane == 0) { sq[row] = s; minbits[row] = 0x7F800000u; }
}

__global__ __launch_bounds__(256) void koleo_tile_fb(const float* __restrict__ X,
                                                     const float* __restrict__ sq,
                                                     unsigned int* __restrict__ minbits) {
  __shared__ __align__(16) char sA[16384];
  __shared__ __align__(16) char sB[16384];
  int rem = blockIdx.x, ti = 0, rowlen = NT128;
  while (rem >= rowlen) { rem -= rowlen; ++ti; --rowlen; }
  const int tj = ti + rem;
  const int i0 = ti * 128, j0 = tj * 128;
  const int tid = threadIdx.x, lane = tid & 63, wave = tid >> 6;
  const int wr = wave >> 1, wc = wave & 1;
  f32x4 acc[4][4] = {};
  for (int k0 = 0; k0 < DIM; k0 += 64) {
    __syncthreads();
#pragma unroll
    for (int it = 0; it < 8; ++it) {
      const int idx = tid + it * 256;
      const int r = idx >> 4, c4 = idx & 15;
      f32x4 va = *(const f32x4*)(X + (size_t)(i0 + r) * DIM + k0 + c4 * 4);
      f32x4 vb = *(const f32x4*)(X + (size_t)(j0 + r) * DIM + k0 + c4 * 4);
      bf16x4 ha, hb;
      ha[0] = (__bf16)va.x; ha[1] = (__bf16)va.y; ha[2] = (__bf16)va.z; ha[3] = (__bf16)va.w;
      hb[0] = (__bf16)vb.x; hb[1] = (__bf16)vb.y; hb[2] = (__bf16)vb.z; hb[3] = (__bf16)vb.w;
      int off = (r * 128 + c4 * 8) ^ ((r & 7) << 4);
      *(bf16x4*)(sA + off) = ha;
      *(bf16x4*)(sB + off) = hb;
    }
    __syncthreads();
#pragma unroll
    for (int ks = 0; ks < 2; ++ks) {
      bf16x8 af[4], bfr[4];
#pragma unroll
      for (int m = 0; m < 4; ++m) {
        const int ra = wr * 64 + m * 16 + (lane & 15);
        af[m]  = *(const bf16x8*)(sA + ((ra * 128 + ks * 64 + (lane >> 4) * 16) ^ ((ra & 7) << 4)));
        const int rb2 = wc * 64 + m * 16 + (lane & 15);
        bfr[m] = *(const bf16x8*)(sB + ((rb2 * 128 + ks * 64 + (lane >> 4) * 16) ^ ((rb2 & 7) << 4)));
      }
#pragma unroll
      for (int m = 0; m < 4; ++m)
#pragma unroll
        for (int n = 0; n < 4; ++n)
          acc[m][n] = __builtin_amdgcn_mfma_f32_16x16x32_bf16(af[m], bfr[n], acc[m][n], 0, 0, 0);
    }
  }
  const int cg = lane >> 4, cl = lane & 15;
  float sqj[4], colmin[4];
#pragma unroll
  for (int n = 0; n < 4; ++n) { sqj[n] = sq[j0 + wc * 64 + n * 16 + cl]; colmin[n] = INFINITY; }
#pragma unroll
  for (int m = 0; m < 4; ++m) {
#pragma unroll
    for (int r = 0; r < 4; ++r) {
      const int gi = i0 + wr * 64 + m * 16 + cg * 4 + r;
      const float si = sq[gi];
      float rowmin = INFINITY;
#pragma unroll
      for (int n = 0; n < 4; ++n) {
        const int gj = j0 + wc * 64 + n * 16 + cl;
        float d2 = si + sqj[n] - 2.0f * acc[m][n][r];
        d2 = fmaxf(d2, 0.0f);
        if (gi == gj) d2 = INFINITY;
        rowmin = fminf(rowmin, d2);
        colmin[n] = fminf(colmin[n], d2);
      }
      rowmin = fminf(rowmin, __shfl_xor(rowmin, 1, 64));
      rowmin = fminf(rowmin, __shfl_xor(rowmin, 2, 64));
      rowmin = fminf(rowmin, __shfl_xor(rowmin, 4, 64));
      rowmin = fminf(rowmin, __shfl_xor(rowmin, 8, 64));
      if (cl == 0) atomicMin(minbits + gi, __float_as_uint(rowmin));
    }
  }
  if (ti != tj) {
#pragma unroll
    for (int n = 0; n < 4; ++n) {
      float cm = colmin[n];
      cm = fminf(cm, __shfl_xor(cm, 16, 64));
      cm = fminf(cm, __shfl_xor(cm, 32, 64));
      if (cg == 0) atomicMin(minbits + j0 + wc * 64 + n * 16 + cl, __float_as_uint(cm));
    }
  }
}

// ---------------------------------------------------------------------------
// Final: loss = -mean(log(sqrt(min_d2) + eps)), single block
// ---------------------------------------------------------------------------
__global__ __launch_bounds__(1024) void koleo_final(const unsigned int* __restrict__ minbits,
                                                    float* __restrict__ out) {
  __shared__ float wsum[16];
  float s = 0.f;
  for (int i = threadIdx.x; i < NROWS; i += 1024) {
    float d2 = __uint_as_float(minbits[i]);
    s += logf(sqrtf(d2) + 1e-8f);
  }
#pragma unroll
  for (int m = 32; m >= 1; m >>= 1) s += __shfl_xor(s, m, 64);
  const int wv = threadIdx.x >> 6, ln = threadIdx.x & 63;
  if (ln == 0) wsum[wv] = s;
  __syncthreads();
  if (wv == 0) {
    float t = (ln < 16) ? wsum[ln] : 0.f;
#pragma unroll
    for (int m = 8; m >= 1; m >>= 1) t += __shfl_xor(t, m, 64);
    if (ln == 0) out[0] = -t / (float)NROWS;
  }
}

// ---------------------------------------------------------------------------
extern "C" void kernel_launch(void* const* d_in, const int* in_sizes, int n_in,
                              void* d_out, int out_size, void* d_ws, size_t ws_size,
                              hipStream_t stream) {
  const float* X = (const float*)d_in[0];
  float* out = (float*)d_out;
  unsigned int* minbits = (unsigned int*)d_ws;                       // 32 KB
  float* sq = (float*)((char*)d_ws + NROWS * sizeof(unsigned int));  // 32 KB
  char* xbf = (char*)d_ws + 65536;                                   // 6.29 MB

  const size_t need = 65536 + PACK8B;
  if (ws_size >= need) {
    koleo_pack8<<<NROWS / 4, 256, 0, stream>>>(X, sq, minbits, xbf);
    koleo_t32<<<NTIL3, 512, LDSB, stream>>>(xbf, sq, minbits);
  } else {
    koleo_prep_fb<<<NROWS / 4, 256, 0, stream>>>(X, sq, minbits);
    koleo_tile_fb<<<NTILES, 256, 0, stream>>>(X, sq, minbits);
  }
  koleo_final<<<1, 1024, 0, stream>>>(minbits, out);
}

// Round 16
// 70.708 us; speedup vs baseline: 4.0207x; 3.6181x over previous
//
#include <hip/hip_runtime.h>
#include <hip/hip_bf16.h>
#include <math.h>

#define NROWS 8192
#define DIM   768
#define NKB   (DIM / 64)         // 12 k-chunks of 64
#define FCH   8192               // i8 chunk: 128 rows x 64 cols = 8 KB
#define FPAN  (NKB * FCH)        // i8 panel: 128 rows x 768 = 98304 B
#define NT128 (NROWS / 128)      // 64 row-blocks
#define NTILES (NT128 * (NT128 + 1) / 2)   // 2080 upper-tri tiles
#define PACK8B ((size_t)NT128 * FPAN)      // 6.29 MB
#define QS    24.0f              // i8 quant scale (clip at ±5.29 sigma)
#define QIS2  (1.0f / (QS * QS))

typedef __attribute__((ext_vector_type(4))) float  f32x4;
typedef __attribute__((ext_vector_type(8))) __bf16 bf16x8;
typedef __attribute__((ext_vector_type(4))) __bf16 bf16x4;
typedef __attribute__((ext_vector_type(4))) int    i32x4;

__device__ __forceinline__ void gload_lds16(const void* g, void* l) {
  __builtin_amdgcn_global_load_lds(
      (const __attribute__((address_space(1))) void*)g,
      (__attribute__((address_space(3))) void*)l, 16, 0, 0);
}

// ---------------------------------------------------------------------------
// Kernel A: fused i8-quantize + prep. One wave per row. f32 -> exact f32
// sq-norm AND i8 quantization (q = rn(clamp(x*24, -127, 127))) into ROW-MAJOR
// 64B-row chunk layout with the R7-class 16B-granule XOR swizzle PRE-APPLIED:
//   chunk(rb, kb) = 128 rows x 64 k; element (r,c) at (r*64 + c) ^ (((r>>1)&3)<<4)
// 4B stores (c%4==0): XOR touches bits 4-5 only -> stays inside one 16B
// granule; XOR constant per row -> global stores remain coalesced.
// Integer dot is exact; d2 noise sigma ~0.9 < fp8 version that passed.
// ---------------------------------------------------------------------------
__global__ __launch_bounds__(256) void koleo_packq(const float* __restrict__ X,
                                                   float* __restrict__ sq,
                                                   unsigned int* __restrict__ minbits,
                                                   char* __restrict__ xbf) {
  const int row  = blockIdx.x * 4 + (threadIdx.x >> 6);
  const int lane = threadIdx.x & 63;
  const int rb = row >> 7, rr = row & 127;
  const int swz = ((rr >> 1) & 3) << 4;
  const float* xr = X + (size_t)row * DIM;
  float s = 0.f;
#pragma unroll
  for (int i = 0; i < 3; ++i) {            // 768 = 3 * 64 lanes * 4 floats
    const int c0 = lane * 4 + i * 256;
    f32x4 v = *(const f32x4*)(xr + c0);
    s += v.x * v.x + v.y * v.y + v.z * v.z + v.w * v.w;
    const int q0 = (int)rintf(fminf(fmaxf(v.x * QS, -127.f), 127.f));
    const int q1 = (int)rintf(fminf(fmaxf(v.y * QS, -127.f), 127.f));
    const int q2 = (int)rintf(fminf(fmaxf(v.z * QS, -127.f), 127.f));
    const int q3 = (int)rintf(fminf(fmaxf(v.w * QS, -127.f), 127.f));
    const int pk = (q0 & 0xff) | ((q1 & 0xff) << 8) |
                   ((q2 & 0xff) << 16) | ((q3 & 0xff) << 24);
    const int kb = c0 >> 6;
    const int c  = c0 & 63;
    const int off = (rr * 64 + c) ^ swz;
    *(int*)(xbf + (size_t)rb * FPAN + (size_t)kb * FCH + off) = pk;
  }
#pragma unroll
  for (int m = 32; m >= 1; m >>= 1) s += __shfl_xor(s, m, 64);
  if (lane == 0) {
    sq[row]      = s;
    minbits[row] = 0x7F800000u;            // +inf
  }
}

// ---------------------------------------------------------------------------
// Kernel B: STRICT R7 CLONE with i8 core. 128x128 upper-triangular Gram
// tiles, 4 waves (2x2 of 64x64), 2-phase dbuf (issue next chunk's 8
// global_load_lds first, compute, vmcnt(0), one barrier). LDS 2x16 KB ->
// 4 blocks/CU. Per chunk: 8x ds_read_b128 (one i32x4 = K=64 fragment per
// row-block, addr pattern byte-identical to R7's measured-0-conflict reads)
// + 16x v_mfma_i32_16x16x64_i8 (2x rate, plain 4-VGPR operands - no MX
// register hazard). Tile ordering = L2 segments (validated R6).
// ---------------------------------------------------------------------------
__global__ __launch_bounds__(256, 4) void koleo_tileq(const char* __restrict__ xbf,
                                                      const float* __restrict__ sq,
                                                      unsigned int* __restrict__ minbits) {
  extern __shared__ char lds[];            // 32768 bytes

  // segment-ordered tile map
  const int b = blockIdx.x;
  int ti, tj;
  if (b < 528) {                           // T0: panels [0,32)
    int rem = b, rl = 32; ti = 0;
    while (rem >= rl) { rem -= rl; ++ti; --rl; }
    tj = ti + rem;
  } else if (b < 1552) {                   // rect bands ti:[0,32) x tj:[32+8q,40+8q)
    const int q = (b - 528) >> 8, rr = (b - 528) & 255;
    ti = rr >> 3; tj = 32 + q * 8 + (rr & 7);
  } else {                                 // T1: panels [32,64)
    int rem = b - 1552, rl = 32; ti = 32;
    while (rem >= rl) { rem -= rl; ++ti; --rl; }
    tj = ti + rem;
  }
  const int i0 = ti * 128, j0 = tj * 128;

  const int tid  = threadIdx.x;
  const int lane = tid & 63;
  const int wave = tid >> 6;               // 0..3
  const int wr   = wave >> 1;              // row half
  const int wc   = wave & 1;               // col half
  const int g16  = (lane >> 4) * 16;       // k-quarter byte offset (K=64: 16B each)

  const char* pA = xbf + (size_t)ti * FPAN + wave * 1024 + lane * 16;
  const char* pB = xbf + (size_t)tj * FPAN + wave * 1024 + lane * 16;

  i32x4 acc[4][4] = {};

  // ---- prologue: stage K-chunk 0 into buffer 0 ---------------------------
#pragma unroll
  for (int h = 0; h < 2; ++h) {
    gload_lds16(pA + h * 4096, lds +        h * 4096 + wave * 1024);
    gload_lds16(pB + h * 4096, lds + 8192 + h * 4096 + wave * 1024);
  }
  asm volatile("s_waitcnt vmcnt(0)" ::: "memory");
  __builtin_amdgcn_s_barrier();

  // ---- main K-loop: one barrier per K-chunk ------------------------------
  for (int t = 0; t < NKB; ++t) {
    char* buf  = lds + (t & 1) * 16384;
    char* nbuf = lds + ((t + 1) & 1) * 16384;
    const bool more = (t + 1 < NKB);

    if (more) {                            // issue next-chunk staging FIRST
      const char* sA = pA + (size_t)(t + 1) * FCH;
      const char* sB = pB + (size_t)(t + 1) * FCH;
#pragma unroll
      for (int h = 0; h < 2; ++h) {
        gload_lds16(sA + h * 4096, nbuf +        h * 4096 + wave * 1024);
        gload_lds16(sB + h * 4096, nbuf + 8192 + h * 4096 + wave * 1024);
      }
    }

    // 8x ds_read_b128: one K=64 i8 fragment (16B) per row-block
    i32x4 aP[4], bP[4];
#pragma unroll
    for (int m = 0; m < 4; ++m) {
      const int ra = wr * 64 + m * 16 + (lane & 15);
      aP[m] = *(const i32x4*)(buf + ((ra * 64 + g16) ^ (((ra >> 1) & 3) << 4)));
      const int rb2 = wc * 64 + m * 16 + (lane & 15);
      bP[m] = *(const i32x4*)(buf + 8192 + ((rb2 * 64 + g16) ^ (((rb2 >> 1) & 3) << 4)));
    }
#pragma unroll
    for (int m = 0; m < 4; ++m)
#pragma unroll
      for (int n = 0; n < 4; ++n)
        acc[m][n] = __builtin_amdgcn_mfma_i32_16x16x64_i8(aP[m], bP[n], acc[m][n], 0, 0, 0);

    if (more) asm volatile("s_waitcnt vmcnt(0)" ::: "memory");
    __builtin_amdgcn_s_barrier();
  }

  // ---- epilogue: d2 = si + sj - 2*dot/S^2, diag mask, row+col min ---------
  // C/D layout (m89, dtype/shape-determined): col = lane&15, row=(lane>>4)*4+reg
  const int cg = lane >> 4;
  const int cl = lane & 15;
  float sqj[4], colmin[4];
#pragma unroll
  for (int n = 0; n < 4; ++n) {
    sqj[n]    = sq[j0 + wc * 64 + n * 16 + cl];
    colmin[n] = INFINITY;
  }
#pragma unroll
  for (int m = 0; m < 4; ++m) {
#pragma unroll
    for (int r = 0; r < 4; ++r) {
      const int gi = i0 + wr * 64 + m * 16 + cg * 4 + r;
      const float si = sq[gi];
      float rowmin = INFINITY;
#pragma unroll
      for (int n = 0; n < 4; ++n) {
        const int gj = j0 + wc * 64 + n * 16 + cl;
        float d2 = si + sqj[n] - 2.0f * QIS2 * (float)acc[m][n][r];
        d2 = fmaxf(d2, 0.0f);
        if (gi == gj) d2 = INFINITY;
        rowmin    = fminf(rowmin, d2);
        colmin[n] = fminf(colmin[n], d2);
      }
      rowmin = fminf(rowmin, __shfl_xor(rowmin, 1, 64));
      rowmin = fminf(rowmin, __shfl_xor(rowmin, 2, 64));
      rowmin = fminf(rowmin, __shfl_xor(rowmin, 4, 64));
      rowmin = fminf(rowmin, __shfl_xor(rowmin, 8, 64));
      if (cl == 0)
        atomicMin(minbits + gi, __float_as_uint(rowmin));
    }
  }
  if (ti != tj) {
#pragma unroll
    for (int n = 0; n < 4; ++n) {
      float cm = colmin[n];
      cm = fminf(cm, __shfl_xor(cm, 16, 64));
      cm = fminf(cm, __shfl_xor(cm, 32, 64));
      if (cg == 0)
        atomicMin(minbits + j0 + wc * 64 + n * 16 + cl, __float_as_uint(cm));
    }
  }
}

// ---------------------------------------------------------------------------
// Fallback (ws too small): bf16 f32-load + in-loop cvt staging, 128^2 tiles.
// ---------------------------------------------------------------------------
__global__ __launch_bounds__(256) void koleo_prep_fb(const float* __restrict__ X,
                                                     float* __restrict__ sq,
                                                     unsigned int* __restrict__ minbits) {
  const int row  = blockIdx.x * 4 + (threadIdx.x >> 6);
  const int lane = threadIdx.x & 63;
  const float* xr = X + (size_t)row * DIM;
  float s = 0.f;
#pragma unroll
  for (int i = 0; i < 3; ++i) {
    f32x4 v = *(const f32x4*)(xr + lane * 4 + i * 256);
    s += v.x * v.x + v.y * v.y + v.z * v.z + v.w * v.w;
  }
#pragma unroll
  for (int m = 32; m >= 1; m >>= 1) s += __shfl_xor(s, m, 64);
  if (lane == 0) { sq[row] = s; minbits[row] = 0x7F800000u; }
}

__global__ __launch_bounds__(256) void koleo_tile_fb(const float* __restrict__ X,
                                                     const float* __restrict__ sq,
                                                     unsigned int* __restrict__ minbits) {
  __shared__ __align__(16) char sA[16384];
  __shared__ __align__(16) char sB[16384];
  int rem = blockIdx.x, ti = 0, rowlen = NT128;
  while (rem >= rowlen) { rem -= rowlen; ++ti; --rowlen; }
  const int tj = ti + rem;
  const int i0 = ti * 128, j0 = tj * 128;
  const int tid = threadIdx.x, lane = tid & 63, wave = tid >> 6;
  const int wr = wave >> 1, wc = wave & 1;
  f32x4 acc[4][4] = {};
  for (int k0 = 0; k0 < DIM; k0 += 64) {
    __syncthreads();
#pragma unroll
    for (int it = 0; it < 8; ++it) {
      const int idx = tid + it * 256;
      const int r = idx >> 4, c4 = idx & 15;
      f32x4 va = *(const f32x4*)(X + (size_t)(i0 + r) * DIM + k0 + c4 * 4);
      f32x4 vb = *(const f32x4*)(X + (size_t)(j0 + r) * DIM + k0 + c4 * 4);
      bf16x4 ha, hb;
      ha[0] = (__bf16)va.x; ha[1] = (__bf16)va.y; ha[2] = (__bf16)va.z; ha[3] = (__bf16)va.w;
      hb[0] = (__bf16)vb.x; hb[1] = (__bf16)vb.y; hb[2] = (__bf16)vb.z; hb[3] = (__bf16)vb.w;
      int off = (r * 128 + c4 * 8) ^ ((r & 7) << 4);
      *(bf16x4*)(sA + off) = ha;
      *(bf16x4*)(sB + off) = hb;
    }
    __syncthreads();
#pragma unroll
    for (int ks = 0; ks < 2; ++ks) {
      bf16x8 af[4], bfr[4];
#pragma unroll
      for (int m = 0; m < 4; ++m) {
        const int ra = wr * 64 + m * 16 + (lane & 15);
        af[m]  = *(const bf16x8*)(sA + ((ra * 128 + ks * 64 + (lane >> 4) * 16) ^ ((ra & 7) << 4)));
        const int rb2 = wc * 64 + m * 16 + (lane & 15);
        bfr[m] = *(const bf16x8*)(sB + ((rb2 * 128 + ks * 64 + (lane >> 4) * 16) ^ ((rb2 & 7) << 4)));
      }
#pragma unroll
      for (int m = 0; m < 4; ++m)
#pragma unroll
        for (int n = 0; n < 4; ++n)
          acc[m][n] = __builtin_amdgcn_mfma_f32_16x16x32_bf16(af[m], bfr[n], acc[m][n], 0, 0, 0);
    }
  }
  const int cg = lane >> 4, cl = lane & 15;
  float sqj[4], colmin[4];
#pragma unroll
  for (int n = 0; n < 4; ++n) { sqj[n] = sq[j0 + wc * 64 + n * 16 + cl]; colmin[n] = INFINITY; }
#pragma unroll
  for (int m = 0; m < 4; ++m) {
#pragma unroll
    for (int r = 0; r < 4; ++r) {
      const int gi = i0 + wr * 64 + m * 16 + cg * 4 + r;
      const float si = sq[gi];
      float rowmin = INFINITY;
#pragma unroll
      for (int n = 0; n < 4; ++n) {
        const int gj = j0 + wc * 64 + n * 16 + cl;
        float d2 = si + sqj[n] - 2.0f * acc[m][n][r];
        d2 = fmaxf(d2, 0.0f);
        if (gi == gj) d2 = INFINITY;
        rowmin = fminf(rowmin, d2);
        colmin[n] = fminf(colmin[n], d2);
      }
      rowmin = fminf(rowmin, __shfl_xor(rowmin, 1, 64));
      rowmin = fminf(rowmin, __shfl_xor(rowmin, 2, 64));
      rowmin = fminf(rowmin, __shfl_xor(rowmin, 4, 64));
      rowmin = fminf(rowmin, __shfl_xor(rowmin, 8, 64));
      if (cl == 0) atomicMin(minbits + gi, __float_as_uint(rowmin));
    }
  }
  if (ti != tj) {
#pragma unroll
    for (int n = 0; n < 4; ++n) {
      float cm = colmin[n];
      cm = fminf(cm, __shfl_xor(cm, 16, 64));
      cm = fminf(cm, __shfl_xor(cm, 32, 64));
      if (cg == 0) atomicMin(minbits + j0 + wc * 64 + n * 16 + cl, __float_as_uint(cm));
    }
  }
}

// ---------------------------------------------------------------------------
// Final: loss = -mean(log(sqrt(min_d2) + eps)), single block
// ---------------------------------------------------------------------------
__global__ __launch_bounds__(1024) void koleo_final(const unsigned int* __restrict__ minbits,
                                                    float* __restrict__ out) {
  __shared__ float wsum[16];
  float s = 0.f;
  for (int i = threadIdx.x; i < NROWS; i += 1024) {
    float d2 = __uint_as_float(minbits[i]);
    s += logf(sqrtf(d2) + 1e-8f);
  }
#pragma unroll
  for (int m = 32; m >= 1; m >>= 1) s += __shfl_xor(s, m, 64);
  const int wv = threadIdx.x >> 6, ln = threadIdx.x & 63;
  if (ln == 0) wsum[wv] = s;
  __syncthreads();
  if (wv == 0) {
    float t = (ln < 16) ? wsum[ln] : 0.f;
#pragma unroll
    for (int m = 8; m >= 1; m >>= 1) t += __shfl_xor(t, m, 64);
    if (ln == 0) out[0] = -t / (float)NROWS;
  }
}

// ---------------------------------------------------------------------------
extern "C" void kernel_launch(void* const* d_in, const int* in_sizes, int n_in,
                              void* d_out, int out_size, void* d_ws, size_t ws_size,
                              hipStream_t stream) {
  const float* X = (const float*)d_in[0];
  float* out = (float*)d_out;
  unsigned int* minbits = (unsigned int*)d_ws;                       // 32 KB
  float* sq = (float*)((char*)d_ws + NROWS * sizeof(unsigned int));  // 32 KB
  char* xbf = (char*)d_ws + 65536;                                   // 6.29 MB

  const size_t need = 65536 + PACK8B;
  if (ws_size >= need) {
    koleo_packq<<<NROWS / 4, 256, 0, stream>>>(X, sq, minbits, xbf);
    koleo_tileq<<<NTILES, 256, 32768, stream>>>(xbf, sq, minbits);
  } else {
    koleo_prep_fb<<<NROWS / 4, 256, 0, stream>>>(X, sq, minbits);
    koleo_tile_fb<<<NTILES, 256, 0, stream>>>(X, sq, minbits);
  }
  koleo_final<<<1, 1024, 0, stream>>>(minbits, out);
}

// Round 17
// 65.160 us; speedup vs baseline: 4.3631x; 1.0851x over previous
//
#include <hip/hip_runtime.h>
#include <hip/hip_bf16.h>
#include <math.h>

#define NROWS 8192
#define DIM   768
#define NKB   (DIM / 64)         // 12 k-chunks of 64
#define FCH   8192               // fp8 chunk: 128 rows x 64 cols = 8 KB
#define FPAN  (NKB * FCH)        // fp8 panel: 128 rows x 768 = 98304 B
#define NT128 (NROWS / 128)      // 64 row-blocks
#define NTILES (NT128 * (NT128 + 1) / 2)   // 2080 upper-tri tiles
#define PACK8B ((size_t)NT128 * FPAN)      // 6.29 MB

typedef __attribute__((ext_vector_type(4))) float  f32x4;
typedef __attribute__((ext_vector_type(8))) __bf16 bf16x8;
typedef __attribute__((ext_vector_type(4))) __bf16 bf16x4;
typedef __attribute__((ext_vector_type(2))) long   longx2;

__device__ __forceinline__ void gload_lds16(const void* g, void* l) {
  __builtin_amdgcn_global_load_lds(
      (const __attribute__((address_space(1))) void*)g,
      (__attribute__((address_space(3))) void*)l, 16, 0, 0);
}

// ---------------------------------------------------------------------------
// Kernel A (CHAMPION R7, verbatim): fused fp8-pack + prep. One wave per row.
// f32 -> exact f32 sq-norm AND fp8 e4m3 conversion (HW v_cvt_pk_fp8_f32) into
// INTERLEAVED chunk layout with the LDS swizzle PRE-APPLIED.
//   chunk(rb, kb) = 128 rows x 64 k-bytes. Within a row, k = ks*32 + g*8 + b
//   is stored at pos = g*16 + ks*8 + b, so ONE b128 read at pos=g*16 yields
//   both k-slices' MFMA fragments.
//   Swizzle: off = (r*64 + pos) ^ (((r>>1)&3)<<4).  [measured: 0 conflicts]
// ---------------------------------------------------------------------------
__global__ __launch_bounds__(256) void koleo_pack8(const float* __restrict__ X,
                                                   float* __restrict__ sq,
                                                   unsigned int* __restrict__ minbits,
                                                   char* __restrict__ xbf) {
  const int row  = blockIdx.x * 4 + (threadIdx.x >> 6);
  const int lane = threadIdx.x & 63;
  const int rb = row >> 7, r = row & 127;
  const float* xr = X + (size_t)row * DIM;
  float s = 0.f;
#pragma unroll
  for (int i = 0; i < 3; ++i) {            // 768 = 3 * 64 lanes * 4 floats
    const int c0 = lane * 4 + i * 256;
    f32x4 v = *(const f32x4*)(xr + c0);
    s += v.x * v.x + v.y * v.y + v.z * v.z + v.w * v.w;
    int pk = __builtin_amdgcn_cvt_pk_fp8_f32(v.x, v.y, 0, false);
    pk     = __builtin_amdgcn_cvt_pk_fp8_f32(v.z, v.w, pk, true);
    const int kb = c0 >> 6;                // chunk index
    const int c  = c0 & 63;                // k within chunk
    const int ks = c >> 5;                 // k-slice 0..1
    const int g  = (c >> 3) & 3;           // lane-quarter group
    const int bb = c & 7;                  // byte in fragment
    const int pos = g * 16 + ks * 8 + bb;  // interleaved position
    const int off = (r * 64 + pos) ^ (((r >> 1) & 3) << 4);
    *(int*)(xbf + (size_t)rb * FPAN + (size_t)kb * FCH + off) = pk;
  }
#pragma unroll
  for (int m = 32; m >= 1; m >>= 1) s += __shfl_xor(s, m, 64);
  if (lane == 0) {
    sq[row]      = s;
    minbits[row] = 0x7F800000u;            // +inf
  }
}

// ---------------------------------------------------------------------------
// Kernel B (CHAMPION R7, verbatim): 128x128 upper-triangular Gram tiles in
// fp8. 2-phase double-buffered loop: issue next K-chunk's global_load_lds
// first, then 8x ds_read_b128 frags + 32 MFMA, then vmcnt(0) + one barrier.
// LDS: 2 x (A 8KB + B 8KB) = 32 KB dynamic; 4 blocks/CU.
// Tile ordering = L2-locality segments (validated R6):
//   [T(0:32): 528] [4 rects 32x8: 4x256] [T(32:64): 528]
// Structural note (R8-R16 exploration): this sits on the measured wall-epoch
// floor (~5300 cyc x 24960 epochs / (4 x 256 CU) ~= 53.8 us). MFMA rate (i8
// 2x: flat), prefetch depth (ring-3: flat), bytes (-24%: flat), epoch
// consolidation (256^2: worse), MX (spills) all failed to move it.
// ---------------------------------------------------------------------------
__global__ __launch_bounds__(256, 4) void koleo_tile8f(const char* __restrict__ xbf,
                                                       const float* __restrict__ sq,
                                                       unsigned int* __restrict__ minbits) {
  extern __shared__ char lds[];            // 32768 bytes

  // segment-ordered tile map
  const int b = blockIdx.x;
  int ti, tj;
  if (b < 528) {                           // T0: panels [0,32)
    int rem = b, rl = 32; ti = 0;
    while (rem >= rl) { rem -= rl; ++ti; --rl; }
    tj = ti + rem;
  } else if (b < 1552) {                   // rect bands ti:[0,32) x tj:[32+8q,40+8q)
    const int q = (b - 528) >> 8, rr = (b - 528) & 255;
    ti = rr >> 3; tj = 32 + q * 8 + (rr & 7);
  } else {                                 // T1: panels [32,64)
    int rem = b - 1552, rl = 32; ti = 32;
    while (rem >= rl) { rem -= rl; ++ti; --rl; }
    tj = ti + rem;
  }
  const int i0 = ti * 128, j0 = tj * 128;

  const int tid  = threadIdx.x;
  const int lane = tid & 63;
  const int wave = tid >> 6;               // 0..3
  const int wr   = wave >> 1;              // row half
  const int wc   = wave & 1;               // col half
  const int g16  = (lane >> 4) * 16;       // fragment 16B group offset

  const char* pA = xbf + (size_t)ti * FPAN + wave * 1024 + lane * 16;
  const char* pB = xbf + (size_t)tj * FPAN + wave * 1024 + lane * 16;

  f32x4 acc[4][4] = {};

  // ---- prologue: stage K-chunk 0 into buffer 0 ---------------------------
#pragma unroll
  for (int h = 0; h < 2; ++h) {
    gload_lds16(pA + h * 4096, lds +        h * 4096 + wave * 1024);
    gload_lds16(pB + h * 4096, lds + 8192 + h * 4096 + wave * 1024);
  }
  asm volatile("s_waitcnt vmcnt(0)" ::: "memory");
  __builtin_amdgcn_s_barrier();

  // ---- main K-loop: one barrier per K-chunk ------------------------------
  for (int t = 0; t < NKB; ++t) {
    char* buf  = lds + (t & 1) * 16384;
    char* nbuf = lds + ((t + 1) & 1) * 16384;
    const bool more = (t + 1 < NKB);

    if (more) {                            // issue next-chunk staging FIRST
      const char* sA = pA + (size_t)(t + 1) * FCH;
      const char* sB = pB + (size_t)(t + 1) * FCH;
#pragma unroll
      for (int h = 0; h < 2; ++h) {
        gload_lds16(sA + h * 4096, nbuf +        h * 4096 + wave * 1024);
        gload_lds16(sB + h * 4096, nbuf + 8192 + h * 4096 + wave * 1024);
      }
    }

    // 8x ds_read_b128: each 16B = [ks0 frag | ks1 frag] for one row
    longx2 aP[4], bP[4];
#pragma unroll
    for (int m = 0; m < 4; ++m) {
      const int ra = wr * 64 + m * 16 + (lane & 15);
      aP[m] = *(const longx2*)(buf + ((ra * 64 + g16) ^ (((ra >> 1) & 3) << 4)));
      const int rb2 = wc * 64 + m * 16 + (lane & 15);
      bP[m] = *(const longx2*)(buf + 8192 + ((rb2 * 64 + g16) ^ (((rb2 >> 1) & 3) << 4)));
    }
#pragma unroll
    for (int ks = 0; ks < 2; ++ks)
#pragma unroll
      for (int m = 0; m < 4; ++m)
#pragma unroll
        for (int n = 0; n < 4; ++n)
          acc[m][n] = __builtin_amdgcn_mfma_f32_16x16x32_fp8_fp8(aP[m][ks], bP[n][ks], acc[m][n], 0, 0, 0);

    if (more) asm volatile("s_waitcnt vmcnt(0)" ::: "memory");
    __builtin_amdgcn_s_barrier();
  }

  // ---- epilogue: d2, diagonal mask, row-min + col-min, atomicMin ----------
  // C/D layout (m89, dtype-independent): col = lane&15, row = (lane>>4)*4+reg
  const int cg = lane >> 4;
  const int cl = lane & 15;
  float sqj[4], colmin[4];
#pragma unroll
  for (int n = 0; n < 4; ++n) {
    sqj[n]    = sq[j0 + wc * 64 + n * 16 + cl];
    colmin[n] = INFINITY;
  }
#pragma unroll
  for (int m = 0; m < 4; ++m) {
#pragma unroll
    for (int r = 0; r < 4; ++r) {
      const int gi = i0 + wr * 64 + m * 16 + cg * 4 + r;
      const float si = sq[gi];
      float rowmin = INFINITY;
#pragma unroll
      for (int n = 0; n < 4; ++n) {
        const int gj = j0 + wc * 64 + n * 16 + cl;
        float d2 = si + sqj[n] - 2.0f * acc[m][n][r];
        d2 = fmaxf(d2, 0.0f);
        if (gi == gj) d2 = INFINITY;
        rowmin    = fminf(rowmin, d2);
        colmin[n] = fminf(colmin[n], d2);
      }
      rowmin = fminf(rowmin, __shfl_xor(rowmin, 1, 64));
      rowmin = fminf(rowmin, __shfl_xor(rowmin, 2, 64));
      rowmin = fminf(rowmin, __shfl_xor(rowmin, 4, 64));
      rowmin = fminf(rowmin, __shfl_xor(rowmin, 8, 64));
      if (cl == 0)
        atomicMin(minbits + gi, __float_as_uint(rowmin));
    }
  }
  if (ti != tj) {
#pragma unroll
    for (int n = 0; n < 4; ++n) {
      float cm = colmin[n];
      cm = fminf(cm, __shfl_xor(cm, 16, 64));
      cm = fminf(cm, __shfl_xor(cm, 32, 64));
      if (cg == 0)
        atomicMin(minbits + j0 + wc * 64 + n * 16 + cl, __float_as_uint(cm));
    }
  }
}

// ---------------------------------------------------------------------------
// Fallback (ws too small): bf16 f32-load + in-loop cvt staging, 128^2 tiles.
// ---------------------------------------------------------------------------
__global__ __launch_bounds__(256) void koleo_prep_fb(const float* __restrict__ X,
                                                     float* __restrict__ sq,
                                                     unsigned int* __restrict__ minbits) {
  const int row  = blockIdx.x * 4 + (threadIdx.x >> 6);
  const int lane = threadIdx.x & 63;
  const float* xr = X + (size_t)row * DIM;
  float s = 0.f;
#pragma unroll
  for (int i = 0; i < 3; ++i) {
    f32x4 v = *(const f32x4*)(xr + lane * 4 + i * 256);
    s += v.x * v.x + v.y * v.y + v.z * v.z + v.w * v.w;
  }
#pragma unroll
  for (int m = 32; m >= 1; m >>= 1) s += __shfl_xor(s, m, 64);
  if (lane == 0) { sq[row] = s; minbits[row] = 0x7F800000u; }
}

__global__ __launch_bounds__(256) void koleo_tile_fb(const float* __restrict__ X,
                                                     const float* __restrict__ sq,
                                                     unsigned int* __restrict__ minbits) {
  __shared__ __align__(16) char sA[16384];
  __shared__ __align__(16) char sB[16384];
  int rem = blockIdx.x, ti = 0, rowlen = NT128;
  while (rem >= rowlen) { rem -= rowlen; ++ti; --rowlen; }
  const int tj = ti + rem;
  const int i0 = ti * 128, j0 = tj * 128;
  const int tid = threadIdx.x, lane = tid & 63, wave = tid >> 6;
  const int wr = wave >> 1, wc = wave & 1;
  f32x4 acc[4][4] = {};
  for (int k0 = 0; k0 < DIM; k0 += 64) {
    __syncthreads();
#pragma unroll
    for (int it = 0; it < 8; ++it) {
      const int idx = tid + it * 256;
      const int r = idx >> 4, c4 = idx & 15;
      f32x4 va = *(const f32x4*)(X + (size_t)(i0 + r) * DIM + k0 + c4 * 4);
      f32x4 vb = *(const f32x4*)(X + (size_t)(j0 + r) * DIM + k0 + c4 * 4);
      bf16x4 ha, hb;
      ha[0] = (__bf16)va.x; ha[1] = (__bf16)va.y; ha[2] = (__bf16)va.z; ha[3] = (__bf16)va.w;
      hb[0] = (__bf16)vb.x; hb[1] = (__bf16)vb.y; hb[2] = (__bf16)vb.z; hb[3] = (__bf16)vb.w;
      int off = (r * 128 + c4 * 8) ^ ((r & 7) << 4);
      *(bf16x4*)(sA + off) = ha;
      *(bf16x4*)(sB + off) = hb;
    }
    __syncthreads();
#pragma unroll
    for (int ks = 0; ks < 2; ++ks) {
      bf16x8 af[4], bfr[4];
#pragma unroll
      for (int m = 0; m < 4; ++m) {
        const int ra = wr * 64 + m * 16 + (lane & 15);
        af[m]  = *(const bf16x8*)(sA + ((ra * 128 + ks * 64 + (lane >> 4) * 16) ^ ((ra & 7) << 4)));
        const int rb2 = wc * 64 + m * 16 + (lane & 15);
        bfr[m] = *(const bf16x8*)(sB + ((rb2 * 128 + ks * 64 + (lane >> 4) * 16) ^ ((rb2 & 7) << 4)));
      }
#pragma unroll
      for (int m = 0; m < 4; ++m)
#pragma unroll
        for (int n = 0; n < 4; ++n)
          acc[m][n] = __builtin_amdgcn_mfma_f32_16x16x32_bf16(af[m], bfr[n], acc[m][n], 0, 0, 0);
    }
  }
  const int cg = lane >> 4, cl = lane & 15;
  float sqj[4], colmin[4];
#pragma unroll
  for (int n = 0; n < 4; ++n) { sqj[n] = sq[j0 + wc * 64 + n * 16 + cl]; colmin[n] = INFINITY; }
#pragma unroll
  for (int m = 0; m < 4; ++m) {
#pragma unroll
    for (int r = 0; r < 4; ++r) {
      const int gi = i0 + wr * 64 + m * 16 + cg * 4 + r;
      const float si = sq[gi];
      float rowmin = INFINITY;
#pragma unroll
      for (int n = 0; n < 4; ++n) {
        const int gj = j0 + wc * 64 + n * 16 + cl;
        float d2 = si + sqj[n] - 2.0f * acc[m][n][r];
        d2 = fmaxf(d2, 0.0f);
        if (gi == gj) d2 = INFINITY;
        rowmin = fminf(rowmin, d2);
        colmin[n] = fminf(colmin[n], d2);
      }
      rowmin = fminf(rowmin, __shfl_xor(rowmin, 1, 64));
      rowmin = fminf(rowmin, __shfl_xor(rowmin, 2, 64));
      rowmin = fminf(rowmin, __shfl_xor(rowmin, 4, 64));
      rowmin = fminf(rowmin, __shfl_xor(rowmin, 8, 64));
      if (cl == 0) atomicMin(minbits + gi, __float_as_uint(rowmin));
    }
  }
  if (ti != tj) {
#pragma unroll
    for (int n = 0; n < 4; ++n) {
      float cm = colmin[n];
      cm = fminf(cm, __shfl_xor(cm, 16, 64));
      cm = fminf(cm, __shfl_xor(cm, 32, 64));
      if (cg == 0) atomicMin(minbits + j0 + wc * 64 + n * 16 + cl, __float_as_uint(cm));
    }
  }
}

// ---------------------------------------------------------------------------
// Final: loss = -mean(log(sqrt(min_d2) + eps)), single block
// ---------------------------------------------------------------------------
__global__ __launch_bounds__(1024) void koleo_final(const unsigned int* __restrict__ minbits,
                                                    float* __restrict__ out) {
  __shared__ float wsum[16];
  float s = 0.f;
  for (int i = threadIdx.x; i < NROWS; i += 1024) {
    float d2 = __uint_as_float(minbits[i]);
    s += logf(sqrtf(d2) + 1e-8f);
  }
#pragma unroll
  for (int m = 32; m >= 1; m >>= 1) s += __shfl_xor(s, m, 64);
  const int wv = threadIdx.x >> 6, ln = threadIdx.x & 63;
  if (ln == 0) wsum[wv] = s;
  __syncthreads();
  if (wv == 0) {
    float t = (ln < 16) ? wsum[ln] : 0.f;
#pragma unroll
    for (int m = 8; m >= 1; m >>= 1) t += __shfl_xor(t, m, 64);
    if (ln == 0) out[0] = -t / (float)NROWS;
  }
}

// ---------------------------------------------------------------------------
extern "C" void kernel_launch(void* const* d_in, const int* in_sizes, int n_in,
                              void* d_out, int out_size, void* d_ws, size_t ws_size,
                              hipStream_t stream) {
  const float* X = (const float*)d_in[0];
  float* out = (float*)d_out;
  unsigned int* minbits = (unsigned int*)d_ws;                       // 32 KB
  float* sq = (float*)((char*)d_ws + NROWS * sizeof(unsigned int));  // 32 KB
  char* xbf = (char*)d_ws + 65536;                                   // 6.29 MB

  const size_t need = 65536 + PACK8B;
  if (ws_size >= need) {
    koleo_pack8<<<NROWS / 4, 256, 0, stream>>>(X, sq, minbits, xbf);
    koleo_tile8f<<<NTILES, 256, 32768, stream>>>(xbf, sq, minbits);
  } else {
    koleo_prep_fb<<<NROWS / 4, 256, 0, stream>>>(X, sq, minbits);
    koleo_tile_fb<<<NTILES, 256, 0, stream>>>(X, sq, minbits);
  }
  koleo_final<<<1, 1024, 0, stream>>>(minbits, out);
}

// Round 18
// 64.046 us; speedup vs baseline: 4.4389x; 1.0174x over previous
//
#include <hip/hip_runtime.h>
#include <hip/hip_bf16.h>
#include <math.h>

#define NROWS 8192
#define DIM   768
#define NKB   (DIM / 64)         // 12 k-chunks of 64
#define FCH   8192               // fp8 chunk: 128 rows x 64 cols = 8 KB
#define FPAN  (NKB * FCH)        // fp8 panel: 128 rows x 768 = 98304 B
#define NT128 (NROWS / 128)      // 64 row-blocks
#define NTILES (NT128 * (NT128 + 1) / 2)   // 2080 upper-tri tiles
#define PACK8B ((size_t)NT128 * FPAN)      // 6.29 MB

typedef __attribute__((ext_vector_type(4))) float  f32x4;
typedef __attribute__((ext_vector_type(8))) __bf16 bf16x8;
typedef __attribute__((ext_vector_type(4))) __bf16 bf16x4;
typedef __attribute__((ext_vector_type(2))) long   longx2;

__device__ __forceinline__ void gload_lds16(const void* g, void* l) {
  __builtin_amdgcn_global_load_lds(
      (const __attribute__((address_space(1))) void*)g,
      (__attribute__((address_space(3))) void*)l, 16, 0, 0);
}

// ---------------------------------------------------------------------------
// Kernel A (CHAMPION R7 + out zero-init): fused fp8-pack + prep. One wave per
// row. f32 -> exact f32 sq-norm AND fp8 e4m3 conversion (HW v_cvt_pk_fp8_f32)
// into INTERLEAVED chunk layout with the LDS swizzle PRE-APPLIED.
//   chunk(rb, kb) = 128 rows x 64 k-bytes. Within a row, k = ks*32 + g*8 + b
//   is stored at pos = g*16 + ks*8 + b, so ONE b128 read at pos=g*16 yields
//   both k-slices' MFMA fragments.
//   Swizzle: off = (r*64 + pos) ^ (((r>>1)&3)<<4).  [measured: 0 conflicts]
// Also zeroes out[0] (stream-ordered before koleo_final32's atomicAdds;
// re-runs every call -> graph-replay safe).
// ---------------------------------------------------------------------------
__global__ __launch_bounds__(256) void koleo_pack8(const float* __restrict__ X,
                                                   float* __restrict__ sq,
                                                   unsigned int* __restrict__ minbits,
                                                   char* __restrict__ xbf,
                                                   float* __restrict__ out) {
  if (blockIdx.x == 0 && threadIdx.x == 0) out[0] = 0.f;
  const int row  = blockIdx.x * 4 + (threadIdx.x >> 6);
  const int lane = threadIdx.x & 63;
  const int rb = row >> 7, r = row & 127;
  const float* xr = X + (size_t)row * DIM;
  float s = 0.f;
#pragma unroll
  for (int i = 0; i < 3; ++i) {            // 768 = 3 * 64 lanes * 4 floats
    const int c0 = lane * 4 + i * 256;
    f32x4 v = *(const f32x4*)(xr + c0);
    s += v.x * v.x + v.y * v.y + v.z * v.z + v.w * v.w;
    int pk = __builtin_amdgcn_cvt_pk_fp8_f32(v.x, v.y, 0, false);
    pk     = __builtin_amdgcn_cvt_pk_fp8_f32(v.z, v.w, pk, true);
    const int kb = c0 >> 6;                // chunk index
    const int c  = c0 & 63;                // k within chunk
    const int ks = c >> 5;                 // k-slice 0..1
    const int g  = (c >> 3) & 3;           // lane-quarter group
    const int bb = c & 7;                  // byte in fragment
    const int pos = g * 16 + ks * 8 + bb;  // interleaved position
    const int off = (r * 64 + pos) ^ (((r >> 1) & 3) << 4);
    *(int*)(xbf + (size_t)rb * FPAN + (size_t)kb * FCH + off) = pk;
  }
#pragma unroll
  for (int m = 32; m >= 1; m >>= 1) s += __shfl_xor(s, m, 64);
  if (lane == 0) {
    sq[row]      = s;
    minbits[row] = 0x7F800000u;            // +inf
  }
}

// ---------------------------------------------------------------------------
// Kernel B (CHAMPION R7, verbatim): 128x128 upper-triangular Gram tiles in
// fp8. 2-phase double-buffered loop: issue next K-chunk's global_load_lds
// first, then 8x ds_read_b128 frags + 32 MFMA, then vmcnt(0) + one barrier.
// LDS: 2 x (A 8KB + B 8KB) = 32 KB dynamic; 4 blocks/CU.
// Tile ordering = L2-locality segments (validated R6):
//   [T(0:32): 528] [4 rects 32x8: 4x256] [T(32:64): 528]
// Structural note (R8-R16 exploration): this sits on the measured wall-epoch
// floor (~5300 cyc x 24960 epochs / (4 x 256 CU) ~= 53.8 us). MFMA rate (i8
// 2x: flat), prefetch depth (ring-3: flat), bytes (-24%: flat), epoch
// consolidation (256^2: worse), MX (spills) all failed to move it.
// ---------------------------------------------------------------------------
__global__ __launch_bounds__(256, 4) void koleo_tile8f(const char* __restrict__ xbf,
                                                       const float* __restrict__ sq,
                                                       unsigned int* __restrict__ minbits) {
  extern __shared__ char lds[];            // 32768 bytes

  // segment-ordered tile map
  const int b = blockIdx.x;
  int ti, tj;
  if (b < 528) {                           // T0: panels [0,32)
    int rem = b, rl = 32; ti = 0;
    while (rem >= rl) { rem -= rl; ++ti; --rl; }
    tj = ti + rem;
  } else if (b < 1552) {                   // rect bands ti:[0,32) x tj:[32+8q,40+8q)
    const int q = (b - 528) >> 8, rr = (b - 528) & 255;
    ti = rr >> 3; tj = 32 + q * 8 + (rr & 7);
  } else {                                 // T1: panels [32,64)
    int rem = b - 1552, rl = 32; ti = 32;
    while (rem >= rl) { rem -= rl; ++ti; --rl; }
    tj = ti + rem;
  }
  const int i0 = ti * 128, j0 = tj * 128;

  const int tid  = threadIdx.x;
  const int lane = tid & 63;
  const int wave = tid >> 6;               // 0..3
  const int wr   = wave >> 1;              // row half
  const int wc   = wave & 1;               // col half
  const int g16  = (lane >> 4) * 16;       // fragment 16B group offset

  const char* pA = xbf + (size_t)ti * FPAN + wave * 1024 + lane * 16;
  const char* pB = xbf + (size_t)tj * FPAN + wave * 1024 + lane * 16;

  f32x4 acc[4][4] = {};

  // ---- prologue: stage K-chunk 0 into buffer 0 ---------------------------
#pragma unroll
  for (int h = 0; h < 2; ++h) {
    gload_lds16(pA + h * 4096, lds +        h * 4096 + wave * 1024);
    gload_lds16(pB + h * 4096, lds + 8192 + h * 4096 + wave * 1024);
  }
  asm volatile("s_waitcnt vmcnt(0)" ::: "memory");
  __builtin_amdgcn_s_barrier();

  // ---- main K-loop: one barrier per K-chunk ------------------------------
  for (int t = 0; t < NKB; ++t) {
    char* buf  = lds + (t & 1) * 16384;
    char* nbuf = lds + ((t + 1) & 1) * 16384;
    const bool more = (t + 1 < NKB);

    if (more) {                            // issue next-chunk staging FIRST
      const char* sA = pA + (size_t)(t + 1) * FCH;
      const char* sB = pB + (size_t)(t + 1) * FCH;
#pragma unroll
      for (int h = 0; h < 2; ++h) {
        gload_lds16(sA + h * 4096, nbuf +        h * 4096 + wave * 1024);
        gload_lds16(sB + h * 4096, nbuf + 8192 + h * 4096 + wave * 1024);
      }
    }

    // 8x ds_read_b128: each 16B = [ks0 frag | ks1 frag] for one row
    longx2 aP[4], bP[4];
#pragma unroll
    for (int m = 0; m < 4; ++m) {
      const int ra = wr * 64 + m * 16 + (lane & 15);
      aP[m] = *(const longx2*)(buf + ((ra * 64 + g16) ^ (((ra >> 1) & 3) << 4)));
      const int rb2 = wc * 64 + m * 16 + (lane & 15);
      bP[m] = *(const longx2*)(buf + 8192 + ((rb2 * 64 + g16) ^ (((rb2 >> 1) & 3) << 4)));
    }
#pragma unroll
    for (int ks = 0; ks < 2; ++ks)
#pragma unroll
      for (int m = 0; m < 4; ++m)
#pragma unroll
        for (int n = 0; n < 4; ++n)
          acc[m][n] = __builtin_amdgcn_mfma_f32_16x16x32_fp8_fp8(aP[m][ks], bP[n][ks], acc[m][n], 0, 0, 0);

    if (more) asm volatile("s_waitcnt vmcnt(0)" ::: "memory");
    __builtin_amdgcn_s_barrier();
  }

  // ---- epilogue: d2, diagonal mask, row-min + col-min, atomicMin ----------
  // C/D layout (m89, dtype-independent): col = lane&15, row = (lane>>4)*4+reg
  const int cg = lane >> 4;
  const int cl = lane & 15;
  float sqj[4], colmin[4];
#pragma unroll
  for (int n = 0; n < 4; ++n) {
    sqj[n]    = sq[j0 + wc * 64 + n * 16 + cl];
    colmin[n] = INFINITY;
  }
#pragma unroll
  for (int m = 0; m < 4; ++m) {
#pragma unroll
    for (int r = 0; r < 4; ++r) {
      const int gi = i0 + wr * 64 + m * 16 + cg * 4 + r;
      const float si = sq[gi];
      float rowmin = INFINITY;
#pragma unroll
      for (int n = 0; n < 4; ++n) {
        const int gj = j0 + wc * 64 + n * 16 + cl;
        float d2 = si + sqj[n] - 2.0f * acc[m][n][r];
        d2 = fmaxf(d2, 0.0f);
        if (gi == gj) d2 = INFINITY;
        rowmin    = fminf(rowmin, d2);
        colmin[n] = fminf(colmin[n], d2);
      }
      rowmin = fminf(rowmin, __shfl_xor(rowmin, 1, 64));
      rowmin = fminf(rowmin, __shfl_xor(rowmin, 2, 64));
      rowmin = fminf(rowmin, __shfl_xor(rowmin, 4, 64));
      rowmin = fminf(rowmin, __shfl_xor(rowmin, 8, 64));
      if (cl == 0)
        atomicMin(minbits + gi, __float_as_uint(rowmin));
    }
  }
  if (ti != tj) {
#pragma unroll
    for (int n = 0; n < 4; ++n) {
      float cm = colmin[n];
      cm = fminf(cm, __shfl_xor(cm, 16, 64));
      cm = fminf(cm, __shfl_xor(cm, 32, 64));
      if (cg == 0)
        atomicMin(minbits + j0 + wc * 64 + n * 16 + cl, __float_as_uint(cm));
    }
  }
}

// ---------------------------------------------------------------------------
// Fallback (ws too small): bf16 f32-load + in-loop cvt staging, 128^2 tiles.
// ---------------------------------------------------------------------------
__global__ __launch_bounds__(256) void koleo_prep_fb(const float* __restrict__ X,
                                                     float* __restrict__ sq,
                                                     unsigned int* __restrict__ minbits,
                                                     float* __restrict__ out) {
  if (blockIdx.x == 0 && threadIdx.x == 0) out[0] = 0.f;
  const int row  = blockIdx.x * 4 + (threadIdx.x >> 6);
  const int lane = threadIdx.x & 63;
  const float* xr = X + (size_t)row * DIM;
  float s = 0.f;
#pragma unroll
  for (int i = 0; i < 3; ++i) {
    f32x4 v = *(const f32x4*)(xr + lane * 4 + i * 256);
    s += v.x * v.x + v.y * v.y + v.z * v.z + v.w * v.w;
  }
#pragma unroll
  for (int m = 32; m >= 1; m >>= 1) s += __shfl_xor(s, m, 64);
  if (lane == 0) { sq[row] = s; minbits[row] = 0x7F800000u; }
}

__global__ __launch_bounds__(256) void koleo_tile_fb(const float* __restrict__ X,
                                                     const float* __restrict__ sq,
                                                     unsigned int* __restrict__ minbits) {
  __shared__ __align__(16) char sA[16384];
  __shared__ __align__(16) char sB[16384];
  int rem = blockIdx.x, ti = 0, rowlen = NT128;
  while (rem >= rowlen) { rem -= rowlen; ++ti; --rowlen; }
  const int tj = ti + rem;
  const int i0 = ti * 128, j0 = tj * 128;
  const int tid = threadIdx.x, lane = tid & 63, wave = tid >> 6;
  const int wr = wave >> 1, wc = wave & 1;
  f32x4 acc[4][4] = {};
  for (int k0 = 0; k0 < DIM; k0 += 64) {
    __syncthreads();
#pragma unroll
    for (int it = 0; it < 8; ++it) {
      const int idx = tid + it * 256;
      const int r = idx >> 4, c4 = idx & 15;
      f32x4 va = *(const f32x4*)(X + (size_t)(i0 + r) * DIM + k0 + c4 * 4);
      f32x4 vb = *(const f32x4*)(X + (size_t)(j0 + r) * DIM + k0 + c4 * 4);
      bf16x4 ha, hb;
      ha[0] = (__bf16)va.x; ha[1] = (__bf16)va.y; ha[2] = (__bf16)va.z; ha[3] = (__bf16)va.w;
      hb[0] = (__bf16)vb.x; hb[1] = (__bf16)vb.y; hb[2] = (__bf16)vb.z; hb[3] = (__bf16)vb.w;
      int off = (r * 128 + c4 * 8) ^ ((r & 7) << 4);
      *(bf16x4*)(sA + off) = ha;
      *(bf16x4*)(sB + off) = hb;
    }
    __syncthreads();
#pragma unroll
    for (int ks = 0; ks < 2; ++ks) {
      bf16x8 af[4], bfr[4];
#pragma unroll
      for (int m = 0; m < 4; ++m) {
        const int ra = wr * 64 + m * 16 + (lane & 15);
        af[m]  = *(const bf16x8*)(sA + ((ra * 128 + ks * 64 + (lane >> 4) * 16) ^ ((ra & 7) << 4)));
        const int rb2 = wc * 64 + m * 16 + (lane & 15);
        bfr[m] = *(const bf16x8*)(sB + ((rb2 * 128 + ks * 64 + (lane >> 4) * 16) ^ ((rb2 & 7) << 4)));
      }
#pragma unroll
      for (int m = 0; m < 4; ++m)
#pragma unroll
        for (int n = 0; n < 4; ++n)
          acc[m][n] = __builtin_amdgcn_mfma_f32_16x16x32_bf16(af[m], bfr[n], acc[m][n], 0, 0, 0);
    }
  }
  const int cg = lane >> 4, cl = lane & 15;
  float sqj[4], colmin[4];
#pragma unroll
  for (int n = 0; n < 4; ++n) { sqj[n] = sq[j0 + wc * 64 + n * 16 + cl]; colmin[n] = INFINITY; }
#pragma unroll
  for (int m = 0; m < 4; ++m) {
#pragma unroll
    for (int r = 0; r < 4; ++r) {
      const int gi = i0 + wr * 64 + m * 16 + cg * 4 + r;
      const float si = sq[gi];
      float rowmin = INFINITY;
#pragma unroll
      for (int n = 0; n < 4; ++n) {
        const int gj = j0 + wc * 64 + n * 16 + cl;
        float d2 = si + sqj[n] - 2.0f * acc[m][n][r];
        d2 = fmaxf(d2, 0.0f);
        if (gi == gj) d2 = INFINITY;
        rowmin = fminf(rowmin, d2);
        colmin[n] = fminf(colmin[n], d2);
      }
      rowmin = fminf(rowmin, __shfl_xor(rowmin, 1, 64));
      rowmin = fminf(rowmin, __shfl_xor(rowmin, 2, 64));
      rowmin = fminf(rowmin, __shfl_xor(rowmin, 4, 64));
      rowmin = fminf(rowmin, __shfl_xor(rowmin, 8, 64));
      if (cl == 0) atomicMin(minbits + gi, __float_as_uint(rowmin));
    }
  }
  if (ti != tj) {
#pragma unroll
    for (int n = 0; n < 4; ++n) {
      float cm = colmin[n];
      cm = fminf(cm, __shfl_xor(cm, 16, 64));
      cm = fminf(cm, __shfl_xor(cm, 32, 64));
      if (cg == 0) atomicMin(minbits + j0 + wc * 64 + n * 16 + cl, __float_as_uint(cm));
    }
  }
}

// ---------------------------------------------------------------------------
// Final (R18: parallel): 32 blocks x 256 threads, one row per thread.
// Wave shfl-reduce, then one atomicAdd(-partial/N) per wave (128 atomics).
// out[0] zeroed by pack kernel (stream-ordered earlier in the same call).
// ---------------------------------------------------------------------------
__global__ __launch_bounds__(256) void koleo_final32(const unsigned int* __restrict__ minbits,
                                                     float* __restrict__ out) {
  const int i = blockIdx.x * 256 + threadIdx.x;
  const float d2 = __uint_as_float(minbits[i]);
  float s = logf(sqrtf(d2) + 1e-8f);
#pragma unroll
  for (int m = 32; m >= 1; m >>= 1) s += __shfl_xor(s, m, 64);
  if ((threadIdx.x & 63) == 0)
    atomicAdd(out, -s * (1.0f / (float)NROWS));
}

// ---------------------------------------------------------------------------
extern "C" void kernel_launch(void* const* d_in, const int* in_sizes, int n_in,
                              void* d_out, int out_size, void* d_ws, size_t ws_size,
                              hipStream_t stream) {
  const float* X = (const float*)d_in[0];
  float* out = (float*)d_out;
  unsigned int* minbits = (unsigned int*)d_ws;                       // 32 KB
  float* sq = (float*)((char*)d_ws + NROWS * sizeof(unsigned int));  // 32 KB
  char* xbf = (char*)d_ws + 65536;                                   // 6.29 MB

  const size_t need = 65536 + PACK8B;
  if (ws_size >= need) {
    koleo_pack8<<<NROWS / 4, 256, 0, stream>>>(X, sq, minbits, xbf, out);
    koleo_tile8f<<<NTILES, 256, 32768, stream>>>(xbf, sq, minbits);
  } else {
    koleo_prep_fb<<<NROWS / 4, 256, 0, stream>>>(X, sq, minbits, out);
    koleo_tile_fb<<<NTILES, 256, 0, stream>>>(X, sq, minbits);
  }
  koleo_final32<<<NROWS / 256, 256, 0, stream>>>(minbits, out);
}